// Round 7
// baseline (174.140 us; speedup 1.0000x reference)
//
#include <hip/hip_runtime.h>
#include <hip/hip_bf16.h>
#include <stdint.h>

#define NN 8192
#define FIN 512
#define HID 256

typedef short bf16x8 __attribute__((ext_vector_type(8)));
typedef float f32x4 __attribute__((ext_vector_type(4)));

__device__ __forceinline__ uint32_t pk2(float lo, float hi) {
  uint32_t a = __float_as_uint(lo), b = __float_as_uint(hi);
  a = (a + 0x7FFFu + ((a >> 16) & 1u)) >> 16;
  b = (b + 0x7FFFu + ((b >> 16) & 1u)) >> 16;
  return a | (b << 16);
}

// workspace byte offsets
#define OFF_SEQB   0u         // 8192*512*2  = 8388608
#define OFF_WTB    8388608u   // 256*512*2   = 262144
#define OFF_FTST   8650752u   // 256*8192*2  = 4194304 (packed swizzled tiles)
#define OFF_F1     12845056u  // 8192*4
#define OFF_F2     12877824u  // 8192*4
#define OFF_Z      12910592u  // 8192*4
#define OFF_F2MAX  12943360u  // 4

// ---- seq f32 -> bf16 ----
__global__ void k_cvt_seq(const float* __restrict__ seq, short* __restrict__ seqb) {
  int i = (blockIdx.x * 256 + threadIdx.x) * 4;
  float4 v = *(const float4*)(seq + i);
  uint2 o; o.x = pk2(v.x, v.y); o.y = pk2(v.z, v.w);
  *(uint2*)(seqb + i) = o;
}

// ---- W[512,256] -> WT bf16 [256,512] ----
__global__ void k_wt(const float* __restrict__ W, short* __restrict__ WTb) {
  int h = blockIdx.x;
  int t = threadIdx.x;
  int k = t * 2;
  float w0 = W[k * 256 + h], w1 = W[(k + 1) * 256 + h];
  ((uint32_t*)(WTb + h * 512))[t] = pk2(w0, w1);
}

// ---- projection GEMM: fts = seq@W; epilogue writes PACKED SWIZZLED ftsP, f1, f2, f2max ----
// ftsP layout: per 64-node tile (32KB = 16384 shorts): [h 0..255][slot 0..7][8 bf16]
//   slot s of row h holds nodes j = tile*64 + (s^(h&7))*8 .. +7  (XOR bank swizzle)
__global__ __launch_bounds__(256) void k_proj(
    const short* __restrict__ seqb, const short* __restrict__ WTb,
    const float* __restrict__ a1, const float* __restrict__ b1,
    const float* __restrict__ a2, const float* __restrict__ b2,
    short* __restrict__ ftsP, float* __restrict__ f1g, float* __restrict__ f2g,
    uint32_t* __restrict__ f2maxenc) {
  __shared__ short At[64][72];
  __shared__ float f1a[64], f2a[64];
  const int t = threadIdx.x;
  const int l = t & 63, w = t >> 6;
  const int lr = l & 15, lg = l >> 4;
  const int R0 = blockIdx.x * 64;
  const int srow = t >> 2, scol = (t & 3) * 16;
  f32x4 acc[4][4] = {};
  if (t < 64) { f1a[t] = 0.f; f2a[t] = 0.f; }
  for (int kt = 0; kt < FIN; kt += 64) {
    uint4 s0 = *(const uint4*)(seqb + (size_t)(R0 + srow) * FIN + kt + scol);
    uint4 s1 = *(const uint4*)(seqb + (size_t)(R0 + srow) * FIN + kt + scol + 8);
    __syncthreads();
    *(uint4*)&At[srow][scol] = s0;
    *(uint4*)&At[srow][scol + 8] = s1;
    __syncthreads();
#pragma unroll
    for (int kk = 0; kk < 2; ++kk) {
      bf16x8 af[4];
#pragma unroll
      for (int mf = 0; mf < 4; ++mf)
        af[mf] = *(const bf16x8*)&At[mf * 16 + lr][kk * 32 + lg * 8];
#pragma unroll
      for (int nf = 0; nf < 4; ++nf) {
        int h = w * 64 + nf * 16 + lr;
        bf16x8 bfr = *(const bf16x8*)(WTb + h * FIN + kt + kk * 32 + lg * 8);
#pragma unroll
        for (int mf = 0; mf < 4; ++mf)
          acc[mf][nf] = __builtin_amdgcn_mfma_f32_16x16x32_bf16(af[mf], bfr, acc[mf][nf], 0, 0, 0);
      }
    }
  }
  __syncthreads();
  float a1v[4], a2v[4];
#pragma unroll
  for (int nf = 0; nf < 4; ++nf) {
    int h = w * 64 + nf * 16 + lr;
    a1v[nf] = a1[h]; a2v[nf] = a2[h];
  }
#pragma unroll
  for (int mf = 0; mf < 4; ++mf) {
    const int jo = mf * 16 + lg * 4;
    const int slot = (jo >> 3) ^ (lr & 7);
#pragma unroll
    for (int nf = 0; nf < 4; ++nf) {
      int h = w * 64 + nf * 16 + lr;
      uint2 o; o.x = pk2(acc[mf][nf][0], acc[mf][nf][1]);
      o.y = pk2(acc[mf][nf][2], acc[mf][nf][3]);
      *(uint2*)(ftsP + (size_t)blockIdx.x * 16384 + h * 64 + slot * 8 + (jo & 7)) = o;
    }
#pragma unroll
    for (int e = 0; e < 4; ++e) {
      float p1 = 0.f, p2 = 0.f;
#pragma unroll
      for (int nf = 0; nf < 4; ++nf) { p1 += acc[mf][nf][e] * a1v[nf]; p2 += acc[mf][nf][e] * a2v[nf]; }
#pragma unroll
      for (int m = 8; m >= 1; m >>= 1) { p1 += __shfl_xor(p1, m, 16); p2 += __shfl_xor(p2, m, 16); }
      if (lr == 0) {
        atomicAdd(&f1a[mf * 16 + lg * 4 + e], p1);
        atomicAdd(&f2a[mf * 16 + lg * 4 + e], p2);
      }
    }
  }
  __syncthreads();
  if (t < 64) {
    float v1 = f1a[t] + b1[0];
    float v2 = f2a[t] + b2[0];
    f1g[R0 + t] = v1; f2g[R0 + t] = v2;
    uint32_t u = __float_as_uint(v2);
    u = (u & 0x80000000u) ? ~u : (u | 0x80000000u);
    atomicMax(f2maxenc, u);
  }
}

// ---- fused flash: 32 rows/wave (each B-frag feeds 2 MFMAs -> half the LDS traffic) ----
// 256 thr = 4 waves x 32 rows = 128 rows/block. Grid (64 i, 8 j-chunks) = 512 blocks = 2/CU.
// V tiles: global_load_lds double-buffer (pre-swizzled ftsP); E built in A-frag regs.
// NOTE: E->bf16 pack uses pk2 (bit-exact RNE, proven R2-R5). v_cvt_pk_bf16_f32 inline asm
// was the R6 failure suspect (unverified pair semantics) -- do not reintroduce without an
// isolated A/B correctness probe.
__global__ __launch_bounds__(256, 2) void k_flash(
    const float* __restrict__ bias, const short* __restrict__ ftsP,
    const float* __restrict__ f1g, const float* __restrict__ f2g,
    const uint32_t* __restrict__ f2maxenc,
    float* __restrict__ outacc, float* __restrict__ Zg) {
  __shared__ short Vb[2][16384];  // 2 x 32KB double buffer
  const int t = threadIdx.x;
  const int l = t & 63, wid = t >> 6;
  const int lr = l & 15, lg = l >> 4;
  const int rbase = blockIdx.x * 128 + wid * 32;
  const int rowA = rbase + lr;            // row set 0; set 1 = rowA+16
  const int jbase = blockIdx.y * 1024;
  const int jt0 = jbase >> 6;
  const int NT = 16;

  uint32_t ue = *f2maxenc;
  float f2mx = __uint_as_float((ue & 0x80000000u) ? (ue ^ 0x80000000u) : ~ue);
  float f1v0 = f1g[rowA];
  float f1v1 = f1g[rowA + 16];
  float x0 = f1v0 + f2mx, x1 = f1v1 + f2mx;
  float mr0 = fmaxf(x0, 0.2f * x0);       // exact row max (bias<=0, lrelu monotone)
  float mr1 = fmaxf(x1, 0.2f * x1);

  const float* bp0 = bias + (size_t)rowA * NN + jbase + lg * 8;
  const float* bp1 = bp0 + (size_t)16 * NN;
  const float* qp = f2g + jbase + lg * 8;

  const int s0 = lg ^ (lr & 7);   // kk=0 slot (conflict-free; 0 conflicts measured R4/R5)
  const int s1 = s0 ^ 4;          // kk=1 slot

  f32x4 acc0[16] = {};            // rows rbase..+15 (set 0)
  f32x4 acc1[16] = {};            // rows rbase+16..+31 (set 1)
  float z0 = 0.f, z1 = 0.f;
  float4 bb0[2][2], bb1[2][2], qq[2][2];  // single-buffered, static-indexed

#define STAGE(TT, BUF)                                                          \
  if ((TT) < NT) {                                                              \
    const short* gs = ftsP + (size_t)(jt0 + (TT)) * 16384 + wid * 4096 + l * 8; \
    _Pragma("unroll")                                                           \
    for (int c = 0; c < 8; ++c)                                                 \
      __builtin_amdgcn_global_load_lds(                                         \
          (const __attribute__((address_space(1))) void*)(gs + c * 512),        \
          (__attribute__((address_space(3))) void*)&Vb[(BUF)][wid * 4096 + c * 512], \
          16, 0, 0);                                                            \
  }
#define LOADB(TT)                                                               \
  if ((TT) < NT) {                                                              \
    _Pragma("unroll")                                                           \
    for (int kk = 0; kk < 2; ++kk) {                                            \
      _Pragma("unroll")                                                         \
      for (int h = 0; h < 2; ++h) {                                             \
        bb0[kk][h] = *(const float4*)(bp0 + (TT) * 64 + kk * 32 + h * 4);       \
        bb1[kk][h] = *(const float4*)(bp1 + (TT) * 64 + kk * 32 + h * 4);       \
        qq[kk][h]  = *(const float4*)(qp  + (TT) * 64 + kk * 32 + h * 4);       \
      }                                                                         \
    }                                                                           \
  }
  // E for one row-set, one kk-half: 8 probabilities -> one A-frag (pk2 RNE pack)
#define EHALF(F1V, MR, BBK, QQK, ZACC, AOUT)                                    \
  {                                                                             \
    float p[8];                                                                 \
    _Pragma("unroll")                                                           \
    for (int e = 0; e < 4; ++e) {                                               \
      float s = (F1V) + ((const float*)&QQK[0])[e];                             \
      float ls = fmaxf(s, 0.2f * s);                                            \
      p[e] = __expf(ls + ((const float*)&BBK[0])[e] - (MR));                    \
    }                                                                           \
    _Pragma("unroll")                                                           \
    for (int e = 0; e < 4; ++e) {                                               \
      float s = (F1V) + ((const float*)&QQK[1])[e];                             \
      float ls = fmaxf(s, 0.2f * s);                                            \
      p[4 + e] = __expf(ls + ((const float*)&BBK[1])[e] - (MR));                \
    }                                                                           \
    ZACC += ((p[0] + p[1]) + (p[2] + p[3])) + ((p[4] + p[5]) + (p[6] + p[7]));  \
    union { bf16x8 v; uint32_t u[4]; } A;                                       \
    A.u[0] = pk2(p[0], p[1]); A.u[1] = pk2(p[2], p[3]);                         \
    A.u[2] = pk2(p[4], p[5]); A.u[3] = pk2(p[6], p[7]);                         \
    AOUT = A.v;                                                                 \
  }

  // prologue: tiles 0,1 -> LDS; bias tile 0 -> regs
  STAGE(0, 0)
  STAGE(1, 1)
  LOADB(0)
  __syncthreads();

  for (int tt = 0; tt < NT; ++tt) {
    // ---- E phase: 4 A-frags (2 row-sets x 2 kk) from current bias regs ----
    bf16x8 A0k0, A0k1, A1k0, A1k1;
    EHALF(f1v0, mr0, bb0[0], qq[0], z0, A0k0)
    EHALF(f1v0, mr0, bb0[1], qq[1], z0, A0k1)
    EHALF(f1v1, mr1, bb1[0], qq[0], z1, A1k0)
    EHALF(f1v1, mr1, bb1[1], qq[1], z1, A1k1)

    // bias regs now free: issue next tile's loads (MFMA phase is the slack)
    LOADB(tt + 1)

    // ---- MFMA phase on buf[tt&1]: each B-frag feeds both row-sets ----
    {
      const int cb = tt & 1;
      const short* vr0 = &Vb[cb][lr * 64 + s0 * 8];
      const short* vr1 = &Vb[cb][lr * 64 + s1 * 8];
#pragma unroll
      for (int nf = 0; nf < 16; ++nf) {
        bf16x8 B0 = *(const bf16x8*)(vr0 + nf * 1024);
        acc0[nf] = __builtin_amdgcn_mfma_f32_16x16x32_bf16(A0k0, B0, acc0[nf], 0, 0, 0);
        acc1[nf] = __builtin_amdgcn_mfma_f32_16x16x32_bf16(A1k0, B0, acc1[nf], 0, 0, 0);
      }
#pragma unroll
      for (int nf = 0; nf < 16; ++nf) {
        bf16x8 B1 = *(const bf16x8*)(vr1 + nf * 1024);
        acc0[nf] = __builtin_amdgcn_mfma_f32_16x16x32_bf16(A0k1, B1, acc0[nf], 0, 0, 0);
        acc1[nf] = __builtin_amdgcn_mfma_f32_16x16x32_bf16(A1k1, B1, acc1[nf], 0, 0, 0);
      }
    }

    // ---- all waves done reading buf[tt&1]; restage it with tile tt+2 ----
    __syncthreads();
    STAGE(tt + 2, tt & 1)
  }
#undef STAGE
#undef LOADB
#undef EHALF

  // Z partials (sum over lg groups; lanes sharing lr)
  z0 += __shfl_xor(z0, 16); z0 += __shfl_xor(z0, 32);
  z1 += __shfl_xor(z1, 16); z1 += __shfl_xor(z1, 32);
  if (lg == 0) {
    atomicAdd(&Zg[rowA], z0);
    atomicAdd(&Zg[rowA + 16], z1);
  }

  // numerator partials (C layout: row = lg*4+e, col = nf*16+lr)
#pragma unroll
  for (int nf = 0; nf < 16; ++nf) {
    int col = nf * 16 + lr;
#pragma unroll
    for (int e = 0; e < 4; ++e) {
      atomicAdd(&outacc[(size_t)(rbase + lg * 4 + e) * HID + col], acc0[nf][e]);
      atomicAdd(&outacc[(size_t)(rbase + 16 + lg * 4 + e) * HID + col], acc1[nf][e]);
    }
  }
}

// ---- finalize: out = elu(num/Z + bias_zero) ----
__global__ void k_final(float* __restrict__ outp, const float* __restrict__ Zg,
                        const float* __restrict__ bz) {
  int i4 = (blockIdx.x * 256 + threadIdx.x) * 4;
  int row = i4 >> 8;
  int col = i4 & 255;
  float4 v = *(float4*)(outp + i4);
  float zr = 1.0f / Zg[row];
  float4 b = *(const float4*)(bz + col);
  float r[4] = {v.x * zr + b.x, v.y * zr + b.y, v.z * zr + b.z, v.w * zr + b.w};
#pragma unroll
  for (int e = 0; e < 4; ++e) r[e] = r[e] > 0.f ? r[e] : (__expf(r[e]) - 1.f);
  *(float4*)(outp + i4) = make_float4(r[0], r[1], r[2], r[3]);
}

extern "C" void kernel_launch(void* const* d_in, const int* in_sizes, int n_in,
                              void* d_out, int out_size, void* d_ws, size_t ws_size,
                              hipStream_t stream) {
  const float* seq  = (const float*)d_in[0];
  const float* bias = (const float*)d_in[1];
  const float* W    = (const float*)d_in[2];
  const float* a1   = (const float*)d_in[3];
  const float* b1   = (const float*)d_in[4];
  const float* a2   = (const float*)d_in[5];
  const float* b2   = (const float*)d_in[6];
  const float* bz   = (const float*)d_in[7];
  float* out = (float*)d_out;
  char* ws = (char*)d_ws;
  short* seqb = (short*)(ws + OFF_SEQB);
  short* WTb  = (short*)(ws + OFF_WTB);
  short* ftsP = (short*)(ws + OFF_FTST);
  float* f1g  = (float*)(ws + OFF_F1);
  float* f2g  = (float*)(ws + OFF_F2);
  float* Zg   = (float*)(ws + OFF_Z);
  uint32_t* f2m = (uint32_t*)(ws + OFF_F2MAX);

  hipMemsetAsync(d_out, 0, (size_t)NN * HID * 4, stream);
  hipMemsetAsync(Zg, 0, NN * 4, stream);
  hipMemsetAsync(f2m, 0, 4, stream);

  k_cvt_seq<<<4096, 256, 0, stream>>>(seq, seqb);
  k_wt<<<256, 256, 0, stream>>>(W, WTb);
  k_proj<<<128, 256, 0, stream>>>(seqb, WTb, a1, b1, a2, b2, ftsP, f1g, f2g, f2m);
  k_flash<<<dim3(64, 8), 256, 0, stream>>>(bias, ftsP, f1g, f2g, f2m, out, Zg);
  k_final<<<2048, 256, 0, stream>>>(out, Zg, bz);
}